// Round 1
// baseline (139.472 us; speedup 1.0000x reference)
//
#include <hip/hip_runtime.h>
#include <math.h>

// Problem constants (from setup_inputs): x is (32, 9, 256, 256) fp32.
#define BATCH 32
#define CHANS 9
#define HH 256
#define WW 256
#define RPW 8   // output rows per wave (10 row loads -> 8 output rows, 1.25x read amp)

typedef float f32x4 __attribute__((ext_vector_type(4)));

// One wave (64 lanes x float4 = 256 px wide) computes RPW=8 consecutive output
// rows of one (b,c) plane from RPW+2=10 row loads (all issued up front for MLP).
// Separable conv, vertical-first: t = vertical smooth, u = vertical diff
// (pure VALU, no cross-lane), then one horizontal shuffle pass per output row.
// 9216 waves total (was 36864); read amplification 1.25x (was 2.0x).
__global__ __launch_bounds__(256) void edge_router_kernel(
    const float* __restrict__ x,
    const float* __restrict__ alpha_p,
    const float* __restrict__ scale_p,
    const int*   __restrict__ year,
    float* __restrict__ out)
{
    const int tid   = threadIdx.x;
    const int lane  = tid & 63;
    const int gwave = blockIdx.x * 4 + (tid >> 6);
    const int rb    = gwave & 31;           // 32 row-blocks of 8 rows per plane
    const int plane = gwave >> 5;           // b*CHANS + c
    const int b     = plane / CHANS;
    const int r0    = rb * RPW;
    const int xq    = lane * 4;

    const float* __restrict__ p = x   + (size_t)plane * (HH * WW) + xq;
    float*       __restrict__ q = out + (size_t)plane * (HH * WW) + xq;

    // ---- 10 independent row loads (r0-1 .. r0+8), all in flight ----
    // Static indices only (rows[] must live in registers, not scratch).
    f32x4 rows[RPW + 2];
#pragma unroll
    for (int i = 0; i < RPW + 2; ++i) {
        int y = r0 - 1 + i;
        y = y < 0 ? 0 : (y > HH - 1 ? HH - 1 : y);   // clamp; zeroed below
        rows[i] = *reinterpret_cast<const f32x4*>(p + (size_t)y * WW);
    }
    if (r0 == 0)        rows[0]       = (f32x4)0.f;  // zero 'SAME' pad, top
    if (r0 == HH - RPW) rows[RPW + 1] = (f32x4)0.f;  // zero 'SAME' pad, bottom

    // ---- per-sample operator parameters (uniform across wave) ----
    const int yr = year[b];
    float w0, w1, eps, post;
    if (yr == 2019) {            // sobel
        w0 = 1.f; w1 = 2.f; eps = 1e-8f; post = 1.f;
    } else if (yr == 2020) {     // scharr
        w0 = 3.f; w1 = 10.f; eps = 1e-8f; post = 1.f;
    } else {                     // learnable (2018, 2021)
        const float a = 1.f / (1.f + expf(-alpha_p[0]));
        const float m = 10.f - 8.f * a;          // max|kernel| element
        w0 = (3.f - 2.f * a) / m;
        w1 = 1.f;
        eps = 1e-6f;
        post = 1.f / (1.f + expf(-scale_p[0]));
    }

    // horizontal pass + magnitude for one output row, given vertical terms
    auto finish_row = [&](f32x4 t, f32x4 u, int y) {
        // halo exchange (one shuffle pair per term)
        float tl = __shfl_up(t.w, 1);
        float ul = __shfl_up(u.w, 1);
        if (lane == 0)  { tl = 0.f; ul = 0.f; }    // zero pad x=-1
        float tr = __shfl_down(t.x, 1);
        float ur = __shfl_down(u.x, 1);
        if (lane == 63) { tr = 0.f; ur = 0.f; }    // zero pad x=W

        f32x4 gx, gy;
        gx.x = t.y - tl;   gx.y = t.z - t.x;
        gx.z = t.w - t.y;  gx.w = tr - t.z;
        gy.x = fmaf(w1, u.x, w0 * (ul + u.y));
        gy.y = fmaf(w1, u.y, w0 * (u.x + u.z));
        gy.z = fmaf(w1, u.z, w0 * (u.y + u.w));
        gy.w = fmaf(w1, u.w, w0 * (u.z + ur));

        f32x4 o;
        o.x = sqrtf(fmaf(gx.x, gx.x, fmaf(gy.x, gy.x, eps))) * post;
        o.y = sqrtf(fmaf(gx.y, gx.y, fmaf(gy.y, gy.y, eps))) * post;
        o.z = sqrtf(fmaf(gx.z, gx.z, fmaf(gy.z, gy.z, eps))) * post;
        o.w = sqrtf(fmaf(gx.w, gx.w, fmaf(gy.w, gy.w, eps))) * post;

        // nt store: output is write-once, keep it out of L2 so halo-row
        // reuse (adjacent waves re-reading boundary rows) stays cached.
        __builtin_nontemporal_store(o, reinterpret_cast<f32x4*>(q + (size_t)y * WW));
    };

    // ---- 8 output rows; vertical terms are pure VALU, no cross-lane ----
#pragma unroll
    for (int i = 0; i < RPW; ++i) {
        const f32x4 va = rows[i];
        const f32x4 vb = rows[i + 1];
        const f32x4 vc = rows[i + 2];
        f32x4 t, u;
        t.x = fmaf(w1, vb.x, w0 * (va.x + vc.x));
        t.y = fmaf(w1, vb.y, w0 * (va.y + vc.y));
        t.z = fmaf(w1, vb.z, w0 * (va.z + vc.z));
        t.w = fmaf(w1, vb.w, w0 * (va.w + vc.w));
        u = vc - va;
        finish_row(t, u, r0 + i);
    }
}

extern "C" void kernel_launch(void* const* d_in, const int* in_sizes, int n_in,
                              void* d_out, int out_size, void* d_ws, size_t ws_size,
                              hipStream_t stream) {
    const float* x     = (const float*)d_in[0];
    const float* alpha = (const float*)d_in[1];
    const float* scale = (const float*)d_in[2];
    const int*   year  = (const int*)  d_in[3];
    float* out = (float*)d_out;

    const int waves  = BATCH * CHANS * (HH / RPW);   // 9216 waves, 8 rows each
    const int blocks = waves / 4;                    // 4 waves/block = 2304
    edge_router_kernel<<<blocks, 256, 0, stream>>>(x, alpha, scale, year, out);
}

// Round 3
// 135.531 us; speedup vs baseline: 1.0291x; 1.0291x over previous
//
#include <hip/hip_runtime.h>
#include <math.h>

// Problem constants (from setup_inputs): x is (32, 9, 256, 256) fp32.
#define BATCH 32
#define CHANS 9
#define HH 256
#define WW 256
#define RPW 4   // output rows per wave (6 row loads -> 4 output rows)

typedef float f32x4 __attribute__((ext_vector_type(4)));

// One wave (64 lanes x float4 = full 256-px row) computes RPW=4 consecutive
// output rows of one (b,c) plane from 6 row loads, all issued up front.
// Separable conv, vertical-first: t = vertical smooth, u = vertical diff
// (pure VALU), then one horizontal shuffle pass per output row.
// 18432 waves / 4608 blocks. Blocks XCD-swizzled so each XCD owns contiguous
// planes -> cross-block halo re-reads hit that XCD's L2 (plane = 256 KB << 4 MB).
// VGPR budget kept small (6x4 row regs) to stay at 8 waves/SIMD.
__global__ __launch_bounds__(256) void edge_router_kernel(
    const float* __restrict__ x,
    const float* __restrict__ alpha_p,
    const float* __restrict__ scale_p,
    const int*   __restrict__ year,
    float* __restrict__ out)
{
    const int tid  = threadIdx.x;
    const int lane = tid & 63;

    // Bijective XCD-contiguous swizzle: 4608 blocks = 8 XCDs x 576.
    // HW round-robins blockIdx across XCDs; remap so XCD k gets the
    // contiguous range [k*576, (k+1)*576) of logical blocks.
    const int nblk = (BATCH * CHANS * (HH / RPW)) / 4;  // 4608
    const int bpc  = nblk >> 3;                         // 576
    const int bid  = blockIdx.x;
    const int sbid = (bid & 7) * bpc + (bid >> 3);

    const int gwave = sbid * 4 + (tid >> 6);
    const int rb    = gwave & (HH / RPW - 1);   // 64 row-blocks per plane
    const int plane = gwave >> 6;               // b*CHANS + c
    const int b     = plane / CHANS;
    const int r0    = rb * RPW;
    const int xq    = lane * 4;

    const float* __restrict__ p = x   + (size_t)plane * (HH * WW) + xq;
    float*       __restrict__ q = out + (size_t)plane * (HH * WW) + xq;

    // ---- 6 independent row loads (r0-1 .. r0+4), all in flight ----
    f32x4 rows[RPW + 2];
#pragma unroll
    for (int i = 0; i < RPW + 2; ++i) {
        int y = r0 - 1 + i;
        y = y < 0 ? 0 : (y > HH - 1 ? HH - 1 : y);   // clamp; zeroed below
        rows[i] = *reinterpret_cast<const f32x4*>(p + (size_t)y * WW);
    }
    if (r0 == 0)        rows[0]       = (f32x4)0.f;  // zero 'SAME' pad, top
    if (r0 == HH - RPW) rows[RPW + 1] = (f32x4)0.f;  // zero 'SAME' pad, bottom

    // ---- per-sample operator parameters (uniform across wave) ----
    const int yr = year[b];
    float w0, w1, eps, post;
    if (yr == 2019) {            // sobel
        w0 = 1.f; w1 = 2.f; eps = 1e-8f; post = 1.f;
    } else if (yr == 2020) {     // scharr
        w0 = 3.f; w1 = 10.f; eps = 1e-8f; post = 1.f;
    } else {                     // learnable (2018, 2021)
        const float a = 1.f / (1.f + expf(-alpha_p[0]));
        const float m = 10.f - 8.f * a;          // max|kernel| element
        w0 = (3.f - 2.f * a) / m;
        w1 = 1.f;
        eps = 1e-6f;
        post = 1.f / (1.f + expf(-scale_p[0]));
    }

    // horizontal pass + magnitude for one output row, given vertical terms
    auto finish_row = [&](f32x4 t, f32x4 u, int y) {
        // halo exchange (one shuffle pair per term)
        float tl = __shfl_up(t.w, 1);
        float ul = __shfl_up(u.w, 1);
        if (lane == 0)  { tl = 0.f; ul = 0.f; }    // zero pad x=-1
        float tr = __shfl_down(t.x, 1);
        float ur = __shfl_down(u.x, 1);
        if (lane == 63) { tr = 0.f; ur = 0.f; }    // zero pad x=W

        f32x4 gx, gy;
        gx.x = t.y - tl;   gx.y = t.z - t.x;
        gx.z = t.w - t.y;  gx.w = tr - t.z;
        gy.x = fmaf(w1, u.x, w0 * (ul + u.y));
        gy.y = fmaf(w1, u.y, w0 * (u.x + u.z));
        gy.z = fmaf(w1, u.z, w0 * (u.y + u.w));
        gy.w = fmaf(w1, u.w, w0 * (u.z + ur));

        f32x4 o;
        o.x = sqrtf(fmaf(gx.x, gx.x, fmaf(gy.x, gy.x, eps))) * post;
        o.y = sqrtf(fmaf(gx.y, gx.y, fmaf(gy.y, gy.y, eps))) * post;
        o.z = sqrtf(fmaf(gx.z, gx.z, fmaf(gy.z, gy.z, eps))) * post;
        o.w = sqrtf(fmaf(gx.w, gx.w, fmaf(gy.w, gy.w, eps))) * post;

        // regular store: let L2 aggregate the streaming writes (fills that
        // hit 6.5 TB/s use normal stores; nt regressed in round 1)
        *reinterpret_cast<f32x4*>(q + (size_t)y * WW) = o;
    };

    // ---- 4 output rows; vertical terms are pure VALU, no cross-lane ----
#pragma unroll
    for (int i = 0; i < RPW; ++i) {
        const f32x4 va = rows[i];
        const f32x4 vb = rows[i + 1];
        const f32x4 vc = rows[i + 2];
        f32x4 t, u;
        t.x = fmaf(w1, vb.x, w0 * (va.x + vc.x));
        t.y = fmaf(w1, vb.y, w0 * (va.y + vc.y));
        t.z = fmaf(w1, vb.z, w0 * (va.z + vc.z));
        t.w = fmaf(w1, vb.w, w0 * (va.w + vc.w));
        u = vc - va;
        finish_row(t, u, r0 + i);
    }
}

extern "C" void kernel_launch(void* const* d_in, const int* in_sizes, int n_in,
                              void* d_out, int out_size, void* d_ws, size_t ws_size,
                              hipStream_t stream) {
    const float* x     = (const float*)d_in[0];
    const float* alpha = (const float*)d_in[1];
    const float* scale = (const float*)d_in[2];
    const int*   year  = (const int*)  d_in[3];
    float* out = (float*)d_out;

    const int waves  = BATCH * CHANS * (HH / RPW);   // 18432 waves, 4 rows each
    const int blocks = waves / 4;                    // 4 waves/block = 4608
    edge_router_kernel<<<blocks, 256, 0, stream>>>(x, alpha, scale, year, out);
}

// Round 4
// 132.827 us; speedup vs baseline: 1.0500x; 1.0204x over previous
//
#include <hip/hip_runtime.h>
#include <math.h>

// Problem constants (from setup_inputs): x is (32, 9, 256, 256) fp32.
#define BATCH 32
#define CHANS 9
#define HH 256
#define WW 256

typedef float f32x4 __attribute__((ext_vector_type(4)));
typedef const __attribute__((address_space(1))) void* gas_ptr;  // global AS
typedef __attribute__((address_space(3))) void* las_ptr;        // LDS AS

// Block-cooperative version: one 256-thread block (4 waves) covers 8
// consecutive output rows of one (b,c) plane. The block stages the 10 input
// rows (10 KB) ONCE into LDS via global_load_lds (direct-to-LDS, width 16),
// then each wave computes 2 output rows from LDS (the best-measured wave
// shape from round 0, math unchanged). HBM read amplification drops from
// ~2x (private halo loads, L3 flushed by the poison fill every iteration,
// cross-XCD halo misses) to a topology-independent 1.25x.
// 9216 blocks; LDS 10.25 KB -> 8 blocks/CU (thread-limited), 32 waves/CU.
__global__ __launch_bounds__(256) void edge_router_kernel(
    const float* __restrict__ x,
    const float* __restrict__ alpha_p,
    const float* __restrict__ scale_p,
    const int*   __restrict__ year,
    float* __restrict__ out)
{
    __shared__ float lds[10][WW];   // rows r0-1 .. r0+8 (clamped)

    const int tid  = threadIdx.x;
    const int lane = tid & 63;
    const int w    = tid >> 6;

    const int strip = blockIdx.x & 31;   // 32 strips of 8 rows per plane
    const int plane = blockIdx.x >> 5;   // b*CHANS + c
    const int b     = plane / CHANS;
    const int r0    = strip * 8;         // first output row of this block
    const int xq    = lane * 4;

    const float* __restrict__ p = x   + (size_t)plane * (HH * WW);
    float*       __restrict__ q = out + (size_t)plane * (HH * WW) + xq;

    // ---- cooperative async load of rows r0-1 .. r0+8 into LDS ----
    // global_load_lds: LDS dest is wave-uniform row base; HW writes lane i's
    // 16 B at base + i*16 — exactly matching gaddr = rowbase + i*16 (linear).
    auto load_row = [&](int l) {
        int y = r0 - 1 + l;
        y = y < 0 ? 0 : (y > HH - 1 ? HH - 1 : y);   // clamp; zeroed in regs
        const float* g = p + (size_t)y * WW + xq;
        __builtin_amdgcn_global_load_lds((gas_ptr)g, (las_ptr)&lds[l][0], 16, 0, 0);
    };
    load_row(w);          // waves 0..3 -> rows 0..3
    load_row(w + 4);      // rows 4..7
    if (w < 2) load_row(w + 8);   // rows 8,9 (wave-uniform branch)

    // ---- per-sample operator params (uniform; hides load latency) ----
    const int yr = year[b];
    float w0, w1, eps, post;
    if (yr == 2019) {            // sobel
        w0 = 1.f; w1 = 2.f; eps = 1e-8f; post = 1.f;
    } else if (yr == 2020) {     // scharr
        w0 = 3.f; w1 = 10.f; eps = 1e-8f; post = 1.f;
    } else {                     // learnable (2018, 2021)
        const float a = 1.f / (1.f + expf(-alpha_p[0]));
        const float m = 10.f - 8.f * a;          // max|kernel| element
        w0 = (3.f - 2.f * a) / m;
        w1 = 1.f;
        eps = 1e-6f;
        post = 1.f / (1.f + expf(-scale_p[0]));
    }

    __syncthreads();   // compiler drains vmcnt before s_barrier

    // ---- wave w: output rows R0=r0+2w, R1=R0+1 from LDS rows 2w..2w+3 ----
    const int R0 = r0 + 2 * w;
    const int R1 = R0 + 1;
    f32x4 va = *reinterpret_cast<const f32x4*>(&lds[2 * w + 0][xq]);
    f32x4 vb = *reinterpret_cast<const f32x4*>(&lds[2 * w + 1][xq]);
    f32x4 vc = *reinterpret_cast<const f32x4*>(&lds[2 * w + 2][xq]);
    f32x4 vd = *reinterpret_cast<const f32x4*>(&lds[2 * w + 3][xq]);
    if (R0 == 0)      va = (f32x4)0.f;   // zero 'SAME' pad, top
    if (R1 == HH - 1) vd = (f32x4)0.f;   // zero 'SAME' pad, bottom

    // horizontal pass + magnitude for one output row, given vertical terms
    auto finish_row = [&](f32x4 t, f32x4 u, int y) {
        // halo exchange (one shuffle pair per term)
        float tl = __shfl_up(t.w, 1);
        float ul = __shfl_up(u.w, 1);
        if (lane == 0)  { tl = 0.f; ul = 0.f; }    // zero pad x=-1
        float tr = __shfl_down(t.x, 1);
        float ur = __shfl_down(u.x, 1);
        if (lane == 63) { tr = 0.f; ur = 0.f; }    // zero pad x=W

        f32x4 gx, gy;
        gx.x = t.y - tl;   gx.y = t.z - t.x;
        gx.z = t.w - t.y;  gx.w = tr - t.z;
        gy.x = fmaf(w1, u.x, w0 * (ul + u.y));
        gy.y = fmaf(w1, u.y, w0 * (u.x + u.z));
        gy.z = fmaf(w1, u.z, w0 * (u.y + u.w));
        gy.w = fmaf(w1, u.w, w0 * (u.z + ur));

        f32x4 o;
        o.x = sqrtf(fmaf(gx.x, gx.x, fmaf(gy.x, gy.x, eps))) * post;
        o.y = sqrtf(fmaf(gx.y, gx.y, fmaf(gy.y, gy.y, eps))) * post;
        o.z = sqrtf(fmaf(gx.z, gx.z, fmaf(gy.z, gy.z, eps))) * post;
        o.w = sqrtf(fmaf(gx.w, gx.w, fmaf(gy.w, gy.w, eps))) * post;

        *reinterpret_cast<f32x4*>(q + (size_t)y * WW) = o;
    };

    // ---- vertical terms (pure VALU, no cross-lane) ----
    f32x4 t0, u0, t1, u1;
    t0.x = fmaf(w1, vb.x, w0 * (va.x + vc.x));
    t0.y = fmaf(w1, vb.y, w0 * (va.y + vc.y));
    t0.z = fmaf(w1, vb.z, w0 * (va.z + vc.z));
    t0.w = fmaf(w1, vb.w, w0 * (va.w + vc.w));
    u0 = vc - va;
    t1.x = fmaf(w1, vc.x, w0 * (vb.x + vd.x));
    t1.y = fmaf(w1, vc.y, w0 * (vb.y + vd.y));
    t1.z = fmaf(w1, vc.z, w0 * (vb.z + vd.z));
    t1.w = fmaf(w1, vc.w, w0 * (vb.w + vd.w));
    u1 = vd - vb;

    finish_row(t0, u0, R0);
    finish_row(t1, u1, R1);
}

extern "C" void kernel_launch(void* const* d_in, const int* in_sizes, int n_in,
                              void* d_out, int out_size, void* d_ws, size_t ws_size,
                              hipStream_t stream) {
    const float* x     = (const float*)d_in[0];
    const float* alpha = (const float*)d_in[1];
    const float* scale = (const float*)d_in[2];
    const int*   year  = (const int*)  d_in[3];
    float* out = (float*)d_out;

    const int blocks = BATCH * CHANS * (HH / 8);   // 9216 blocks, 8 rows each
    edge_router_kernel<<<blocks, 256, 0, stream>>>(x, alpha, scale, year, out);
}